// Round 1
// baseline (1100.941 us; speedup 1.0000x reference)
//
#include <hip/hip_runtime.h>

// ---- problem dims (fixed) ----
#define T_TOK 8192      // B*S
#define DMODEL 1024
#define NEXP 8
#define TOPK 2
#define HID 4096
#define NPAIR (T_TOK*TOPK)   // 16384, every token contributes exactly 2 pairs

typedef unsigned short u16;
typedef short s16x8 __attribute__((ext_vector_type(8)));
typedef float f32x4 __attribute__((ext_vector_type(4)));

// fp32 -> bf16 round-to-nearest-even (bit trick)
__device__ __forceinline__ u16 f2b(float f) {
    union { float f; unsigned int u; } v; v.f = f;
    return (u16)((v.u + 0x7fffu + ((v.u >> 16) & 1u)) >> 16);
}

// ---------------- convert x to bf16 ----------------
__global__ __launch_bounds__(256) void cvtx_kernel(const float* __restrict__ x,
                                                   u16* __restrict__ xb) {
    size_t i = ((size_t)blockIdx.x * 256 + threadIdx.x) * 8;
    float4 f0 = *(const float4*)(x + i);
    float4 f1 = *(const float4*)(x + i + 4);
    s16x8 o;
    o[0]=(short)f2b(f0.x); o[1]=(short)f2b(f0.y); o[2]=(short)f2b(f0.z); o[3]=(short)f2b(f0.w);
    o[4]=(short)f2b(f1.x); o[5]=(short)f2b(f1.y); o[6]=(short)f2b(f1.z); o[7]=(short)f2b(f1.w);
    *(s16x8*)(xb + i) = o;
}

// ---------------- router: logits, softmax, top-2, counts ----------------
__global__ __launch_bounds__(256) void router_kernel(
    const float* __restrict__ x, const float* __restrict__ Wr, const float* __restrict__ br,
    int* __restrict__ topi, float* __restrict__ topw, int* __restrict__ cnt)
{
    __shared__ float WrS[NEXP * DMODEL];  // 32 KB
    int tid = threadIdx.x;
    const float4* Wr4 = (const float4*)Wr;
    float4* WrS4 = (float4*)WrS;
    for (int i = tid; i < NEXP * DMODEL / 4; i += 256) WrS4[i] = Wr4[i];
    __syncthreads();

    int wid = tid >> 6, lane = tid & 63;
    int t = blockIdx.x * 4 + wid;
    const float* xr = x + (size_t)t * DMODEL;

    float acc[NEXP];
#pragma unroll
    for (int e = 0; e < NEXP; ++e) acc[e] = 0.f;
    for (int i = lane; i < DMODEL; i += 64) {
        float xv = xr[i];
#pragma unroll
        for (int e = 0; e < NEXP; ++e) acc[e] = fmaf(xv, WrS[e * DMODEL + i], acc[e]);
    }
#pragma unroll
    for (int e = 0; e < NEXP; ++e) {
        float v = acc[e];
#pragma unroll
        for (int off = 32; off > 0; off >>= 1) v += __shfl_xor(v, off);
        acc[e] = v;
    }
    if (lane == 0) {
        float lg[NEXP];
#pragma unroll
        for (int e = 0; e < NEXP; ++e) lg[e] = acc[e] + br[e];
        int i1 = 0;
#pragma unroll
        for (int e = 1; e < NEXP; ++e) if (lg[e] > lg[i1]) i1 = e;  // ties -> lower idx
        int i2 = (i1 == 0) ? 1 : 0;
#pragma unroll
        for (int e = 0; e < NEXP; ++e) if (e != i1 && lg[e] > lg[i2]) i2 = e;
        // renormalized top-2 softmax weights == 2-way softmax of the two logits
        float e2 = expf(lg[i2] - lg[i1]);
        float s = 1.f + e2;
        float w1 = 1.f / s, w2 = e2 / s;
        topi[t * 2] = i1;  topi[t * 2 + 1] = i2;
        topw[t * 2] = w1;  topw[t * 2 + 1] = w2;
        atomicAdd(&cnt[i1], 1);
        atomicAdd(&cnt[i2], 1);
    }
}

__global__ void offsets_kernel(const int* __restrict__ cnt, int* __restrict__ offs) {
    if (threadIdx.x == 0 && blockIdx.x == 0) {
        int a = 0;
        for (int e = 0; e < NEXP; ++e) { offs[e] = a; a += cnt[e]; }
        offs[NEXP] = a;
    }
}

__global__ __launch_bounds__(256) void scatter_kernel(
    const int* __restrict__ topi, const float* __restrict__ topw,
    const int* __restrict__ offs, int* __restrict__ fill,
    int* __restrict__ tok, float* __restrict__ wgt)
{
    int t = blockIdx.x * 256 + threadIdx.x;
#pragma unroll
    for (int s = 0; s < TOPK; ++s) {
        int e = topi[t * 2 + s];
        int pos = atomicAdd(&fill[e], 1);
        int p = offs[e] + pos;
        tok[p] = t;
        wgt[p] = topw[t * 2 + s];
    }
}

// ---------------- grouped GEMM common config ----------------
#define BM 128
#define BN 128
#define BK 64

// GEMM1: H1[p, n] = gelu( sum_d xb[tok[p], d] * W1[e, n, d] + b1[e, n] )
__global__ __launch_bounds__(256) void gemm1_kernel(
    const u16* __restrict__ xb, const float* __restrict__ W1, const float* __restrict__ b1,
    const int* __restrict__ tok, const int* __restrict__ cnt, const int* __restrict__ offs,
    u16* __restrict__ H1, int p0, int p1)
{
    const int e = blockIdx.z;
    const int ce = cnt[e];
    const int row0 = blockIdx.y * BM;
    if (row0 >= ce) return;
    const int oe = offs[e];
    if (oe + min(ce, row0 + BM) <= p0 || oe + row0 >= p1) return;
    const int col0 = blockIdx.x * BN;

    __shared__ __align__(16) u16 As[BM * BK];
    __shared__ __align__(16) u16 Bs[BN * BK];

    const int tid = threadIdx.x;
    const int lane = tid & 63, wid = tid >> 6;
    const int wm = (wid >> 1) * 64, wn = (wid & 1) * 64;

    f32x4 acc[4][4] = {};

    int atok[4];
#pragma unroll
    for (int j = 0; j < 4; ++j) {
        int r = (j * 256 + tid) >> 3;
        int gi = row0 + r;
        atok[j] = (gi < ce) ? tok[oe + gi] : 0;
    }

    for (int kt = 0; kt < DMODEL; kt += BK) {
        s16x8 aC[4], bC[4];
#pragma unroll
        for (int j = 0; j < 4; ++j) {
            int ci = j * 256 + tid; int r = ci >> 3, s = ci & 7;
            aC[j] = *(const s16x8*)(xb + (size_t)atok[j] * DMODEL + kt + s * 8);
            const float* wp = W1 + (size_t)(e * HID + col0 + r) * DMODEL + kt + s * 8;
            float4 f0 = *(const float4*)wp;
            float4 f1 = *(const float4*)(wp + 4);
            s16x8 o;
            o[0]=(short)f2b(f0.x); o[1]=(short)f2b(f0.y); o[2]=(short)f2b(f0.z); o[3]=(short)f2b(f0.w);
            o[4]=(short)f2b(f1.x); o[5]=(short)f2b(f1.y); o[6]=(short)f2b(f1.z); o[7]=(short)f2b(f1.w);
            bC[j] = o;
        }
        __syncthreads();
#pragma unroll
        for (int j = 0; j < 4; ++j) {
            int ci = j * 256 + tid; int r = ci >> 3, s = ci & 7;
            int sl = s ^ (r & 7);                       // XOR swizzle, kills 128B-stride conflict
            *(s16x8*)(As + r * BK + sl * 8) = aC[j];
            *(s16x8*)(Bs + r * BK + sl * 8) = bC[j];
        }
        __syncthreads();
#pragma unroll
        for (int half = 0; half < 2; ++half) {
            s16x8 av[4], bv[4];
            int kslot = half * 4 + (lane >> 4);
#pragma unroll
            for (int mi = 0; mi < 4; ++mi) {
                int r = wm + mi * 16 + (lane & 15);
                av[mi] = *(const s16x8*)(As + r * BK + ((kslot ^ (r & 7)) * 8));
            }
#pragma unroll
            for (int ni = 0; ni < 4; ++ni) {
                int r = wn + ni * 16 + (lane & 15);
                bv[ni] = *(const s16x8*)(Bs + r * BK + ((kslot ^ (r & 7)) * 8));
            }
#pragma unroll
            for (int mi = 0; mi < 4; ++mi)
#pragma unroll
                for (int ni = 0; ni < 4; ++ni)
                    acc[mi][ni] = __builtin_amdgcn_mfma_f32_16x16x32_bf16(av[mi], bv[ni], acc[mi][ni], 0, 0, 0);
        }
    }

    // epilogue: +bias, exact gelu, bf16 store to H1
#pragma unroll
    for (int mi = 0; mi < 4; ++mi) {
#pragma unroll
        for (int j = 0; j < 4; ++j) {
            int r = wm + mi * 16 + ((lane >> 4) * 4) + j;
            int gi = row0 + r;
            int p = oe + gi;
            if (gi < ce && p >= p0 && p < p1) {
                u16* hrow = H1 + (size_t)(p - p0) * HID;
#pragma unroll
                for (int ni = 0; ni < 4; ++ni) {
                    int n = col0 + wn + ni * 16 + (lane & 15);
                    float v = acc[mi][ni][j] + b1[e * HID + n];
                    v = 0.5f * v * (1.0f + erff(v * 0.70710678118654752f));
                    hrow[n] = f2b(v);
                }
            }
        }
    }
}

// GEMM2: out[tok[p], d] += wgt[p] * ( sum_h H1[p, h] * W2[e, d, h] + b2[e, d] )
__global__ __launch_bounds__(256) void gemm2_kernel(
    const u16* __restrict__ H1, const float* __restrict__ W2, const float* __restrict__ b2,
    const int* __restrict__ tok, const float* __restrict__ wgt,
    const int* __restrict__ cnt, const int* __restrict__ offs,
    float* __restrict__ out, int p0, int p1)
{
    const int e = blockIdx.z;
    const int ce = cnt[e];
    const int row0 = blockIdx.y * BM;
    if (row0 >= ce) return;
    const int oe = offs[e];
    if (oe + min(ce, row0 + BM) <= p0 || oe + row0 >= p1) return;
    const int col0 = blockIdx.x * BN;

    __shared__ __align__(16) u16 As[BM * BK];
    __shared__ __align__(16) u16 Bs[BN * BK];

    const int tid = threadIdx.x;
    const int lane = tid & 63, wid = tid >> 6;
    const int wm = (wid >> 1) * 64, wn = (wid & 1) * 64;

    f32x4 acc[4][4] = {};

    const int smax = p1 - p0 - 1;
    int aidx[4];
#pragma unroll
    for (int j = 0; j < 4; ++j) {
        int r = (j * 256 + tid) >> 3;
        int idx = oe + row0 + r - p0;
        aidx[j] = idx < 0 ? 0 : (idx > smax ? smax : idx);  // clamp: OOB rows never stored
    }

    for (int kt = 0; kt < HID; kt += BK) {
        s16x8 aC[4], bC[4];
#pragma unroll
        for (int j = 0; j < 4; ++j) {
            int ci = j * 256 + tid; int r = ci >> 3, s = ci & 7;
            aC[j] = *(const s16x8*)(H1 + (size_t)aidx[j] * HID + kt + s * 8);
            const float* wp = W2 + (size_t)(e * DMODEL + col0 + r) * HID + kt + s * 8;
            float4 f0 = *(const float4*)wp;
            float4 f1 = *(const float4*)(wp + 4);
            s16x8 o;
            o[0]=(short)f2b(f0.x); o[1]=(short)f2b(f0.y); o[2]=(short)f2b(f0.z); o[3]=(short)f2b(f0.w);
            o[4]=(short)f2b(f1.x); o[5]=(short)f2b(f1.y); o[6]=(short)f2b(f1.z); o[7]=(short)f2b(f1.w);
            bC[j] = o;
        }
        __syncthreads();
#pragma unroll
        for (int j = 0; j < 4; ++j) {
            int ci = j * 256 + tid; int r = ci >> 3, s = ci & 7;
            int sl = s ^ (r & 7);
            *(s16x8*)(As + r * BK + sl * 8) = aC[j];
            *(s16x8*)(Bs + r * BK + sl * 8) = bC[j];
        }
        __syncthreads();
#pragma unroll
        for (int half = 0; half < 2; ++half) {
            s16x8 av[4], bv[4];
            int kslot = half * 4 + (lane >> 4);
#pragma unroll
            for (int mi = 0; mi < 4; ++mi) {
                int r = wm + mi * 16 + (lane & 15);
                av[mi] = *(const s16x8*)(As + r * BK + ((kslot ^ (r & 7)) * 8));
            }
#pragma unroll
            for (int ni = 0; ni < 4; ++ni) {
                int r = wn + ni * 16 + (lane & 15);
                bv[ni] = *(const s16x8*)(Bs + r * BK + ((kslot ^ (r & 7)) * 8));
            }
#pragma unroll
            for (int mi = 0; mi < 4; ++mi)
#pragma unroll
                for (int ni = 0; ni < 4; ++ni)
                    acc[mi][ni] = __builtin_amdgcn_mfma_f32_16x16x32_bf16(av[mi], bv[ni], acc[mi][ni], 0, 0, 0);
        }
    }

    // epilogue: +bias, scale by routing weight, scatter-add into out
#pragma unroll
    for (int mi = 0; mi < 4; ++mi) {
#pragma unroll
        for (int j = 0; j < 4; ++j) {
            int r = wm + mi * 16 + ((lane >> 4) * 4) + j;
            int gi = row0 + r;
            int p = oe + gi;
            if (gi < ce && p >= p0 && p < p1) {
                float w = wgt[p];
                float* orow = out + (size_t)tok[p] * DMODEL;
#pragma unroll
                for (int ni = 0; ni < 4; ++ni) {
                    int n = col0 + wn + ni * 16 + (lane & 15);
                    float v = w * (acc[mi][ni][j] + b2[e * DMODEL + n]);
                    atomicAdd(orow + n, v);
                }
            }
        }
    }
}

// ---------------- host launcher ----------------
extern "C" void kernel_launch(void* const* d_in, const int* in_sizes, int n_in,
                              void* d_out, int out_size, void* d_ws, size_t ws_size,
                              hipStream_t stream)
{
    const float* x  = (const float*)d_in[0];
    const float* Wr = (const float*)d_in[1];
    const float* br = (const float*)d_in[2];
    const float* W1 = (const float*)d_in[3];
    const float* b1 = (const float*)d_in[4];
    const float* W2 = (const float*)d_in[5];
    const float* b2 = (const float*)d_in[6];
    float* out = (float*)d_out;

    char* ws = (char*)d_ws;
    u16* xb = (u16*)ws;
    size_t o = (size_t)T_TOK * DMODEL * 2;          // 16 MiB bf16 x
    int* cnt  = (int*)(ws + o);
    int* fill = (int*)(ws + o + 64);
    int* offs = (int*)(ws + o + 128);
    size_t o2 = o + 1024;
    int*   topi = (int*)(ws + o2);
    float* topw = (float*)(ws + o2 + (size_t)T_TOK * 2 * 4);
    int*   tok  = (int*)(ws + o2 + (size_t)T_TOK * 2 * 8);
    float* wgt  = (float*)(ws + o2 + (size_t)T_TOK * 2 * 12);
    size_t oH = o2 + (size_t)T_TOK * 2 * 16;        // H1 slice buffer starts here
    u16* H1 = (u16*)(ws + oH);

    // adapt H1 slice to available workspace (full = 134 MiB -> single slice)
    long long cap = ((long long)ws_size - (long long)oH) / ((long long)HID * 2);
    int slice;
    if (cap >= NPAIR) slice = NPAIR;
    else if (cap < 2048) slice = 2048;   // minimum viable; smaller ws would OOB
    else slice = (int)cap;

    hipMemsetAsync(out, 0, (size_t)out_size * 4, stream);
    hipMemsetAsync(cnt, 0, 256, stream);   // cnt + fill + offs

    cvtx_kernel<<<dim3(T_TOK * DMODEL / 2048), 256, 0, stream>>>(x, xb);
    router_kernel<<<dim3(T_TOK / 4), 256, 0, stream>>>(x, Wr, br, topi, topw, cnt);
    offsets_kernel<<<dim3(1), 64, 0, stream>>>(cnt, offs);
    scatter_kernel<<<dim3(T_TOK / 256), 256, 0, stream>>>(topi, topw, offs, fill, tok, wgt);

    for (int pp = 0; pp < NPAIR; pp += slice) {
        int p1v = pp + slice < NPAIR ? pp + slice : NPAIR;
        gemm1_kernel<<<dim3(HID / BN, 64, NEXP), 256, 0, stream>>>(
            xb, W1, b1, tok, cnt, offs, H1, pp, p1v);
        gemm2_kernel<<<dim3(DMODEL / BN, 64, NEXP), 256, 0, stream>>>(
            H1, W2, b2, tok, wgt, cnt, offs, out, pp, p1v);
    }
}

// Round 2
// 1010.383 us; speedup vs baseline: 1.0896x; 1.0896x over previous
//
#include <hip/hip_runtime.h>

// ---- problem dims (fixed) ----
#define T_TOK 8192      // B*S
#define DMODEL 1024
#define NEXP 8
#define TOPK 2
#define HID 4096
#define NPAIR (T_TOK*TOPK)   // 16384

typedef unsigned short u16;
typedef short s16x8 __attribute__((ext_vector_type(8)));
typedef float f32x4 __attribute__((ext_vector_type(4)));

// fp32 -> bf16 round-to-nearest-even
__device__ __forceinline__ u16 f2b(float f) {
    union { float f; unsigned int u; } v; v.f = f;
    return (u16)((v.u + 0x7fffu + ((v.u >> 16) & 1u)) >> 16);
}

__device__ __forceinline__ s16x8 cvt8(float4 f0, float4 f1) {
    s16x8 o;
    o[0]=(short)f2b(f0.x); o[1]=(short)f2b(f0.y); o[2]=(short)f2b(f0.z); o[3]=(short)f2b(f0.w);
    o[4]=(short)f2b(f1.x); o[5]=(short)f2b(f1.y); o[6]=(short)f2b(f1.z); o[7]=(short)f2b(f1.w);
    return o;
}

// async global->LDS, 16B per lane; LDS dest must be linear in lane order
__device__ __forceinline__ void gload16(const void* g, void* l) {
    __builtin_amdgcn_global_load_lds(
        (const __attribute__((address_space(1))) unsigned int*)g,
        (__attribute__((address_space(3))) unsigned int*)l, 16, 0, 0);
}

// ---------------- generic fp32 -> bf16 conversion (grid-stride, 8/thread) ----------------
__global__ __launch_bounds__(256) void cvt_kernel(const float* __restrict__ in,
                                                  u16* __restrict__ out, long n8) {
    long stride = (long)gridDim.x * 256;
    for (long i = (long)blockIdx.x * 256 + threadIdx.x; i < n8; i += stride) {
        const float4* p = (const float4*)(in + i * 8);
        float4 f0 = p[0], f1 = p[1];
        *(s16x8*)(out + i * 8) = cvt8(f0, f1);
    }
}

// ---------------- router (fp32 throughout; selection must match reference) ----------------
__global__ __launch_bounds__(256) void router_kernel(
    const float* __restrict__ x, const float* __restrict__ Wr, const float* __restrict__ br,
    int* __restrict__ topi, float* __restrict__ topw, int* __restrict__ cnt)
{
    __shared__ float WrS[NEXP * DMODEL];  // 32 KB
    int tid = threadIdx.x;
    const float4* Wr4 = (const float4*)Wr;
    float4* WrS4 = (float4*)WrS;
    for (int i = tid; i < NEXP * DMODEL / 4; i += 256) WrS4[i] = Wr4[i];
    __syncthreads();

    int wid = tid >> 6, lane = tid & 63;
    int t = blockIdx.x * 4 + wid;
    const float* xr = x + (size_t)t * DMODEL;

    float acc[NEXP];
#pragma unroll
    for (int e = 0; e < NEXP; ++e) acc[e] = 0.f;
    for (int i = lane; i < DMODEL; i += 64) {
        float xv = xr[i];
#pragma unroll
        for (int e = 0; e < NEXP; ++e) acc[e] = fmaf(xv, WrS[e * DMODEL + i], acc[e]);
    }
#pragma unroll
    for (int e = 0; e < NEXP; ++e) {
        float v = acc[e];
#pragma unroll
        for (int off = 32; off > 0; off >>= 1) v += __shfl_xor(v, off);
        acc[e] = v;
    }
    if (lane == 0) {
        float lg[NEXP];
#pragma unroll
        for (int e = 0; e < NEXP; ++e) lg[e] = acc[e] + br[e];
        int i1 = 0;
#pragma unroll
        for (int e = 1; e < NEXP; ++e) if (lg[e] > lg[i1]) i1 = e;
        int i2 = (i1 == 0) ? 1 : 0;
#pragma unroll
        for (int e = 0; e < NEXP; ++e) if (e != i1 && lg[e] > lg[i2]) i2 = e;
        float e2 = expf(lg[i2] - lg[i1]);
        float s = 1.f + e2;
        topi[t * 2] = i1;  topi[t * 2 + 1] = i2;
        topw[t * 2] = 1.f / s;  topw[t * 2 + 1] = e2 / s;
        atomicAdd(&cnt[i1], 1);
        atomicAdd(&cnt[i2], 1);
    }
}

__global__ void offsets_kernel(const int* __restrict__ cnt, int* __restrict__ offs) {
    if (threadIdx.x == 0 && blockIdx.x == 0) {
        int a = 0;
        for (int e = 0; e < NEXP; ++e) { offs[e] = a; a += cnt[e]; }
        offs[NEXP] = a;
    }
}

// wave-aggregated scatter: 8 atomics/wave instead of 64
__global__ __launch_bounds__(256) void scatter_kernel(
    const int* __restrict__ topi, const float* __restrict__ topw,
    const int* __restrict__ offs, int* __restrict__ fill,
    int* __restrict__ tok, float* __restrict__ wgt)
{
    int t = blockIdx.x * 256 + threadIdx.x;
    int lane = threadIdx.x & 63;
#pragma unroll
    for (int s = 0; s < TOPK; ++s) {
        int e = topi[t * 2 + s];
        float w = topw[t * 2 + s];
#pragma unroll
        for (int ex = 0; ex < NEXP; ++ex) {
            unsigned long long m = __ballot(e == ex);
            if (e == ex) {
                int ldr = (int)__ffsll((unsigned long long)m) - 1;
                int base = 0;
                if (lane == ldr) base = atomicAdd(&fill[ex], (int)__popcll(m));
                base = __shfl(base, ldr);
                int mypos = base + (int)__popcll(m & ((1ull << lane) - 1ull));
                int p = offs[ex] + mypos;
                tok[p] = t;
                wgt[p] = w;
            }
        }
    }
}

// ---------------- grouped GEMM config ----------------
#define BM 128
#define BN 128
#define BK 64

// GEMM1: H1[p, n] = gelu( sum_d xb[tok[p], d] * W1[e, n, d] + b1[e, n] )
template <bool WB16>
__global__ __launch_bounds__(256) void gemm1_kernel(
    const u16* __restrict__ xb, const float* __restrict__ W1f, const u16* __restrict__ W1b,
    const float* __restrict__ b1,
    const int* __restrict__ tok, const int* __restrict__ cnt, const int* __restrict__ offs,
    u16* __restrict__ H1, int p0, int p1)
{
    const int e = blockIdx.z;
    const int ce = cnt[e];
    const int row0 = blockIdx.y * BM;
    if (row0 >= ce) return;
    const int oe = offs[e];
    if (oe + min(ce, row0 + BM) <= p0 || oe + row0 >= p1) return;
    const int col0 = blockIdx.x * BN;

    __shared__ __align__(16) u16 As[BM * BK];
    __shared__ __align__(16) u16 Bs[BN * BK];

    const int tid = threadIdx.x;
    const int lane = tid & 63, wid = tid >> 6;
    const int wm = (wid >> 1) * 64, wn = (wid & 1) * 64;

    f32x4 acc[4][4] = {};

    // staging-call constants. idx=c*256+tid covers 1024 lanes -> 128 rows x 8 chunks.
    // LDS dest linear at idx*16B; source column chunk pre-swizzled: s = (tid&7)^(r&7).
    size_t aoff[4], boff[4];
#pragma unroll
    for (int c = 0; c < 4; ++c) {
        int idx = c * 256 + tid;
        int r = idx >> 3;
        int s = (tid & 7) ^ (r & 7);
        int gi = row0 + r;
        int tk = (gi < ce) ? tok[oe + gi] : tok[oe];
        aoff[c] = (size_t)tk * DMODEL + (size_t)(s * 8);
        if (WB16) boff[c] = ((size_t)e * HID + col0 + r) * DMODEL + (size_t)(s * 8);
        else      boff[c] = ((size_t)e * HID + col0 + r) * DMODEL + (size_t)((tid & 7) * 8);
    }

    for (int kt = 0; kt < DMODEL; kt += BK) {
        if constexpr (WB16) {
#pragma unroll
            for (int c = 0; c < 4; ++c) {
                int idx = c * 256 + tid;
                gload16(xb + aoff[c] + kt, (char*)As + idx * 16);
                gload16(W1b + boff[c] + kt, (char*)Bs + idx * 16);
            }
            __syncthreads();
        } else {
            s16x8 bC[4];
#pragma unroll
            for (int c = 0; c < 4; ++c) {
                int idx = c * 256 + tid;
                gload16(xb + aoff[c] + kt, (char*)As + idx * 16);
                const float* wp = W1f + boff[c] + kt;
                float4 f0 = ((const float4*)wp)[0], f1 = ((const float4*)wp)[1];
                bC[c] = cvt8(f0, f1);
            }
#pragma unroll
            for (int c = 0; c < 4; ++c) {
                int idx = c * 256 + tid;
                int r = idx >> 3, sl = (tid & 7) ^ (r & 7);
                *(s16x8*)(Bs + r * BK + sl * 8) = bC[c];
            }
            __syncthreads();
        }
#pragma unroll
        for (int half = 0; half < 2; ++half) {
            s16x8 av[4], bv[4];
            int kslot = half * 4 + (lane >> 4);
#pragma unroll
            for (int mi = 0; mi < 4; ++mi) {
                int r = wm + mi * 16 + (lane & 15);
                av[mi] = *(const s16x8*)(As + r * BK + ((kslot ^ (r & 7)) * 8));
            }
#pragma unroll
            for (int ni = 0; ni < 4; ++ni) {
                int r = wn + ni * 16 + (lane & 15);
                bv[ni] = *(const s16x8*)(Bs + r * BK + ((kslot ^ (r & 7)) * 8));
            }
#pragma unroll
            for (int mi = 0; mi < 4; ++mi)
#pragma unroll
                for (int ni = 0; ni < 4; ++ni)
                    acc[mi][ni] = __builtin_amdgcn_mfma_f32_16x16x32_bf16(av[mi], bv[ni], acc[mi][ni], 0, 0, 0);
        }
        __syncthreads();
    }

    // epilogue: +bias, exact gelu, bf16 store
#pragma unroll
    for (int mi = 0; mi < 4; ++mi) {
#pragma unroll
        for (int j = 0; j < 4; ++j) {
            int r = wm + mi * 16 + ((lane >> 4) * 4) + j;
            int gi = row0 + r;
            int p = oe + gi;
            if (gi < ce && p >= p0 && p < p1) {
                u16* hrow = H1 + (size_t)(p - p0) * HID;
#pragma unroll
                for (int ni = 0; ni < 4; ++ni) {
                    int n = col0 + wn + ni * 16 + (lane & 15);
                    float v = acc[mi][ni][j] + b1[e * HID + n];
                    v = 0.5f * v * (1.0f + erff(v * 0.70710678118654752f));
                    hrow[n] = f2b(v);
                }
            }
        }
    }
}

// GEMM2: out[tok[p], d] += wgt[p] * ( sum_h H1[p, h] * W2b[e, d, h] + b2[e, d] )
__global__ __launch_bounds__(256) void gemm2_kernel(
    const u16* __restrict__ H1, const u16* __restrict__ W2b, const float* __restrict__ b2,
    const int* __restrict__ tok, const float* __restrict__ wgt,
    const int* __restrict__ cnt, const int* __restrict__ offs,
    float* __restrict__ out, int p0, int p1)
{
    const int e = blockIdx.z;
    const int ce = cnt[e];
    const int row0 = blockIdx.y * BM;
    if (row0 >= ce) return;
    const int oe = offs[e];
    if (oe + min(ce, row0 + BM) <= p0 || oe + row0 >= p1) return;
    const int col0 = blockIdx.x * BN;

    __shared__ __align__(16) u16 As[BM * BK];
    __shared__ __align__(16) u16 Bs[BN * BK];

    const int tid = threadIdx.x;
    const int lane = tid & 63, wid = tid >> 6;
    const int wm = (wid >> 1) * 64, wn = (wid & 1) * 64;

    f32x4 acc[4][4] = {};

    const int smax = p1 - p0 - 1;
    size_t aoff[4], boff[4];
#pragma unroll
    for (int c = 0; c < 4; ++c) {
        int idx = c * 256 + tid;
        int r = idx >> 3;
        int s = (tid & 7) ^ (r & 7);
        int ai = oe + row0 + r - p0;
        ai = ai < 0 ? 0 : (ai > smax ? smax : ai);
        aoff[c] = (size_t)ai * HID + (size_t)(s * 8);
        boff[c] = ((size_t)e * DMODEL + col0 + r) * HID + (size_t)(s * 8);
    }

    for (int kt = 0; kt < HID; kt += BK) {
#pragma unroll
        for (int c = 0; c < 4; ++c) {
            int idx = c * 256 + tid;
            gload16(H1 + aoff[c] + kt, (char*)As + idx * 16);
            gload16(W2b + boff[c] + kt, (char*)Bs + idx * 16);
        }
        __syncthreads();
#pragma unroll
        for (int half = 0; half < 2; ++half) {
            s16x8 av[4], bv[4];
            int kslot = half * 4 + (lane >> 4);
#pragma unroll
            for (int mi = 0; mi < 4; ++mi) {
                int r = wm + mi * 16 + (lane & 15);
                av[mi] = *(const s16x8*)(As + r * BK + ((kslot ^ (r & 7)) * 8));
            }
#pragma unroll
            for (int ni = 0; ni < 4; ++ni) {
                int r = wn + ni * 16 + (lane & 15);
                bv[ni] = *(const s16x8*)(Bs + r * BK + ((kslot ^ (r & 7)) * 8));
            }
#pragma unroll
            for (int mi = 0; mi < 4; ++mi)
#pragma unroll
                for (int ni = 0; ni < 4; ++ni)
                    acc[mi][ni] = __builtin_amdgcn_mfma_f32_16x16x32_bf16(av[mi], bv[ni], acc[mi][ni], 0, 0, 0);
        }
        __syncthreads();
    }

#pragma unroll
    for (int mi = 0; mi < 4; ++mi) {
#pragma unroll
        for (int j = 0; j < 4; ++j) {
            int r = wm + mi * 16 + ((lane >> 4) * 4) + j;
            int gi = row0 + r;
            int p = oe + gi;
            if (gi < ce && p >= p0 && p < p1) {
                float w = wgt[p];
                float* orow = out + (size_t)tok[p] * DMODEL;
#pragma unroll
                for (int ni = 0; ni < 4; ++ni) {
                    int n = col0 + wn + ni * 16 + (lane & 15);
                    float v = w * (acc[mi][ni][j] + b2[e * DMODEL + n]);
                    atomicAdd(orow + n, v);
                }
            }
        }
    }
}

// ---------------- host launcher ----------------
extern "C" void kernel_launch(void* const* d_in, const int* in_sizes, int n_in,
                              void* d_out, int out_size, void* d_ws, size_t ws_size,
                              hipStream_t stream)
{
    const float* x  = (const float*)d_in[0];
    const float* Wr = (const float*)d_in[1];
    const float* br = (const float*)d_in[2];
    const float* W1 = (const float*)d_in[3];
    const float* b1 = (const float*)d_in[4];
    const float* W2 = (const float*)d_in[5];
    const float* b2 = (const float*)d_in[6];
    float* out = (float*)d_out;

    char* ws = (char*)d_ws;
    u16* xb = (u16*)ws;                              // 16 MiB
    size_t o2 = (size_t)T_TOK * DMODEL * 2;
    int*   cnt  = (int*)(ws + o2);
    int*   fill = (int*)(ws + o2 + 64);
    int*   offs = (int*)(ws + o2 + 128);
    int*   topi = (int*)(ws + o2 + 1024);
    float* topw = (float*)(ws + o2 + 1024 + (size_t)NPAIR * 4);
    int*   tok  = (int*)(ws + o2 + 1024 + (size_t)NPAIR * 8);
    float* wgt  = (float*)(ws + o2 + 1024 + (size_t)NPAIR * 12);

    const size_t WBYTES = (size_t)NEXP * DMODEL * HID * 2;   // 64 MiB each
    size_t oW2 = o2 + (1u << 20);
    size_t oW1 = oW2 + WBYTES;
    size_t oH_t1 = oW1 + WBYTES;

    // tier1: both weights bf16 (needs >= 153 MiB); tier2: only W2 bf16
    bool wb16 = (ws_size >= oH_t1 + (size_t)1024 * HID * 2);
    u16* W2b = (u16*)(ws + oW2);
    u16* W1b = (u16*)(ws + oW1);
    size_t oH = wb16 ? oH_t1 : oW1;
    u16* H1 = (u16*)(ws + oH);

    long long cap = ((long long)ws_size - (long long)oH) / ((long long)HID * 2);
    int slice = cap >= NPAIR ? NPAIR : (cap < 1024 ? 1024 : (int)cap);

    hipMemsetAsync(out, 0, (size_t)out_size * 4, stream);
    hipMemsetAsync(cnt, 0, 256, stream);

    cvt_kernel<<<dim3(1024), 256, 0, stream>>>(x, xb, (long)T_TOK * DMODEL / 8);
    cvt_kernel<<<dim3(2048), 256, 0, stream>>>(W2, W2b, (long)NEXP * DMODEL * HID / 8);
    if (wb16)
        cvt_kernel<<<dim3(2048), 256, 0, stream>>>(W1, W1b, (long)NEXP * DMODEL * HID / 8);

    router_kernel<<<dim3(T_TOK / 4), 256, 0, stream>>>(x, Wr, br, topi, topw, cnt);
    offsets_kernel<<<dim3(1), 64, 0, stream>>>(cnt, offs);
    scatter_kernel<<<dim3(T_TOK / 256), 256, 0, stream>>>(topi, topw, offs, fill, tok, wgt);

    for (int pp = 0; pp < NPAIR; pp += slice) {
        int p1v = pp + slice < NPAIR ? pp + slice : NPAIR;
        if (wb16)
            gemm1_kernel<true><<<dim3(HID / BN, 64, NEXP), 256, 0, stream>>>(
                xb, W1, W1b, b1, tok, cnt, offs, H1, pp, p1v);
        else
            gemm1_kernel<false><<<dim3(HID / BN, 64, NEXP), 256, 0, stream>>>(
                xb, W1, W1b, b1, tok, cnt, offs, H1, pp, p1v);
        gemm2_kernel<<<dim3(DMODEL / BN, 64, NEXP), 256, 0, stream>>>(
            H1, W2b, b2, tok, wgt, cnt, offs, out, pp, p1v);
    }
}

// Round 3
// 893.154 us; speedup vs baseline: 1.2326x; 1.1313x over previous
//
#include <hip/hip_runtime.h>

// ---- problem dims (fixed) ----
#define T_TOK 8192      // B*S
#define DMODEL 1024
#define NEXP 8
#define TOPK 2
#define HID 4096
#define NPAIR (T_TOK*TOPK)   // 16384
#define BM 128
#define BN 128
#define BK 64
#define MAXT (NPAIR/BM + NEXP)   // 136 row-tiles upper bound

typedef unsigned short u16;
typedef unsigned int u32;
typedef short s16x8 __attribute__((ext_vector_type(8)));
typedef float f32x4 __attribute__((ext_vector_type(4)));

// fp32 -> bf16 round-to-nearest-even
__device__ __forceinline__ u16 f2b(float f) {
    union { float f; unsigned int u; } v; v.f = f;
    return (u16)((v.u + 0x7fffu + ((v.u >> 16) & 1u)) >> 16);
}

__device__ __forceinline__ s16x8 cvt8(float4 f0, float4 f1) {
    s16x8 o;
    o[0]=(short)f2b(f0.x); o[1]=(short)f2b(f0.y); o[2]=(short)f2b(f0.z); o[3]=(short)f2b(f0.w);
    o[4]=(short)f2b(f1.x); o[5]=(short)f2b(f1.y); o[6]=(short)f2b(f1.z); o[7]=(short)f2b(f1.w);
    return o;
}

// async global->LDS, 16B per lane; LDS dest linear in lane order
__device__ __forceinline__ void gload16(const void* g, void* l) {
    __builtin_amdgcn_global_load_lds(
        (const __attribute__((address_space(1))) unsigned int*)g,
        (__attribute__((address_space(3))) unsigned int*)l, 16, 0, 0);
}

// tanh-form gelu, exp/rcp in HW; |err vs exact gelu| ~1e-3 absolute
__device__ __forceinline__ float gelu_fast(float v) {
    float y = 0.7978845608028654f * v * fmaf(0.044715f * v, v, 1.0f);
    float t = -2.8853900817779268f * y;   // -2y * log2(e)
    float z, r;
    asm("v_exp_f32 %0, %1" : "=v"(z) : "v"(t));      // e^{-2y}
    float den = 1.0f + z;
    asm("v_rcp_f32 %0, %1" : "=v"(r) : "v"(den));
    return v * r;                                     // v/(1+e^{-2y})
}

// ---------------- fp32 -> bf16 conversion ----------------
__global__ __launch_bounds__(256) void cvt_kernel(const float* __restrict__ in,
                                                  u16* __restrict__ out, long n8) {
    long stride = (long)gridDim.x * 256;
    for (long i = (long)blockIdx.x * 256 + threadIdx.x; i < n8; i += stride) {
        const float4* p = (const float4*)(in + i * 8);
        float4 f0 = p[0], f1 = p[1];
        *(s16x8*)(out + i * 8) = cvt8(f0, f1);
    }
}

// ---------------- router (fp32; selection must match reference) ----------------
__global__ __launch_bounds__(256) void router_kernel(
    const float* __restrict__ x, const float* __restrict__ Wr, const float* __restrict__ br,
    int* __restrict__ topi, float* __restrict__ topw, int* __restrict__ cnt)
{
    __shared__ float WrS[NEXP * DMODEL];
    int tid = threadIdx.x;
    const float4* Wr4 = (const float4*)Wr;
    float4* WrS4 = (float4*)WrS;
    for (int i = tid; i < NEXP * DMODEL / 4; i += 256) WrS4[i] = Wr4[i];
    __syncthreads();

    int wid = tid >> 6, lane = tid & 63;
    int t = blockIdx.x * 4 + wid;
    const float* xr = x + (size_t)t * DMODEL;

    float acc[NEXP];
#pragma unroll
    for (int e = 0; e < NEXP; ++e) acc[e] = 0.f;
    for (int i = lane; i < DMODEL; i += 64) {
        float xv = xr[i];
#pragma unroll
        for (int e = 0; e < NEXP; ++e) acc[e] = fmaf(xv, WrS[e * DMODEL + i], acc[e]);
    }
#pragma unroll
    for (int e = 0; e < NEXP; ++e) {
        float v = acc[e];
#pragma unroll
        for (int off = 32; off > 0; off >>= 1) v += __shfl_xor(v, off);
        acc[e] = v;
    }
    if (lane == 0) {
        float lg[NEXP];
#pragma unroll
        for (int e = 0; e < NEXP; ++e) lg[e] = acc[e] + br[e];
        int i1 = 0;
#pragma unroll
        for (int e = 1; e < NEXP; ++e) if (lg[e] > lg[i1]) i1 = e;
        int i2 = (i1 == 0) ? 1 : 0;
#pragma unroll
        for (int e = 0; e < NEXP; ++e) if (e != i1 && lg[e] > lg[i2]) i2 = e;
        float e2 = expf(lg[i2] - lg[i1]);
        float s = 1.f + e2;
        topi[t * 2] = i1;  topi[t * 2 + 1] = i2;
        topw[t * 2] = 1.f / s;  topw[t * 2 + 1] = e2 / s;
        atomicAdd(&cnt[i1], 1);
        atomicAdd(&cnt[i2], 1);
    }
}

// offsets + compact tile table (single thread; 8+136 iterations)
__global__ void offsets_kernel(const int* __restrict__ cnt, int* __restrict__ offs,
                               u32* __restrict__ table) {
    if (threadIdx.x == 0 && blockIdx.x == 0) {
        int a = 0;
        for (int e = 0; e < NEXP; ++e) { offs[e] = a; a += cnt[e]; }
        offs[NEXP] = a;
        int nt = 0;
        for (int e = 0; e < NEXP; ++e)
            for (int r0 = 0; r0 < cnt[e]; r0 += BM)
                table[nt++] = ((u32)e << 20) | (u32)r0;
        for (; nt < MAXT; ++nt) table[nt] = 0xFFFFFFFFu;
    }
}

// wave-aggregated scatter
__global__ __launch_bounds__(256) void scatter_kernel(
    const int* __restrict__ topi, const float* __restrict__ topw,
    const int* __restrict__ offs, int* __restrict__ fill,
    int* __restrict__ tok, float* __restrict__ wgt)
{
    int t = blockIdx.x * 256 + threadIdx.x;
    int lane = threadIdx.x & 63;
#pragma unroll
    for (int s = 0; s < TOPK; ++s) {
        int e = topi[t * 2 + s];
        float w = topw[t * 2 + s];
#pragma unroll
        for (int ex = 0; ex < NEXP; ++ex) {
            unsigned long long m = __ballot(e == ex);
            if (e == ex) {
                int ldr = (int)__ffsll((unsigned long long)m) - 1;
                int base = 0;
                if (lane == ldr) base = atomicAdd(&fill[ex], (int)__popcll(m));
                base = __shfl(base, ldr);
                int mypos = base + (int)__popcll(m & ((1ull << lane) - 1ull));
                int p = offs[ex] + mypos;
                tok[p] = t;
                wgt[p] = w;
            }
        }
    }
}

// GEMM1: H1[p, n] = gelu( sum_d xb[tok[p], d] * W1b[e, n, d] + b1[e, n] )
__global__ __launch_bounds__(256) void gemm1_kernel(
    const u16* __restrict__ xb, const u16* __restrict__ W1b, const float* __restrict__ b1,
    const int* __restrict__ tok, const int* __restrict__ cnt, const int* __restrict__ offs,
    const u32* __restrict__ table, u16* __restrict__ H1, int p0, int p1)
{
    const int NCOL = HID / BN;                 // 32
    const int nb = NCOL * MAXT, q = nb / 8;
    int bid = blockIdx.x;
    int swz = (bid & 7) * q + (bid >> 3);      // XCD-contiguous logical id
    int tile = swz / NCOL, colb = swz % NCOL;
    u32 entry = table[tile];
    if (entry == 0xFFFFFFFFu) return;
    const int e = (int)(entry >> 20);
    const int row0 = (int)(entry & 0xFFFFFu);
    const int ce = cnt[e], oe = offs[e];
    if (oe + min(ce, row0 + BM) <= p0 || oe + row0 >= p1) return;
    const int col0 = colb * BN;

    __shared__ __align__(16) u16 As[BM * BK];
    __shared__ __align__(16) u16 Bs[BN * BK];

    const int tid = threadIdx.x;
    const int lane = tid & 63, wid = tid >> 6;
    const int wm = (wid >> 1) * 64, wn = (wid & 1) * 64;

    f32x4 acc[4][4] = {};

    size_t aoff[4], boff[4];
#pragma unroll
    for (int c = 0; c < 4; ++c) {
        int idx = c * 256 + tid;
        int r = idx >> 3;
        int s = (tid & 7) ^ (r & 7);           // pre-swizzled source column chunk
        int gi = row0 + r;
        int tk = (gi < ce) ? tok[oe + gi] : tok[oe];
        aoff[c] = (size_t)tk * DMODEL + (size_t)(s * 8);
        boff[c] = ((size_t)e * HID + col0 + r) * DMODEL + (size_t)(s * 8);
    }

    for (int kt = 0; kt < DMODEL; kt += BK) {
#pragma unroll
        for (int c = 0; c < 4; ++c) {
            int idx = c * 256 + tid;
            gload16(xb + aoff[c] + kt, (char*)As + idx * 16);
            gload16(W1b + boff[c] + kt, (char*)Bs + idx * 16);
        }
        __syncthreads();
#pragma unroll
        for (int half = 0; half < 2; ++half) {
            s16x8 av[4], bv[4];
            int kslot = half * 4 + (lane >> 4);
#pragma unroll
            for (int mi = 0; mi < 4; ++mi) {
                int r = wm + mi * 16 + (lane & 15);
                av[mi] = *(const s16x8*)(As + r * BK + ((kslot ^ (r & 7)) * 8));
            }
#pragma unroll
            for (int ni = 0; ni < 4; ++ni) {
                int r = wn + ni * 16 + (lane & 15);
                bv[ni] = *(const s16x8*)(Bs + r * BK + ((kslot ^ (r & 7)) * 8));
            }
#pragma unroll
            for (int mi = 0; mi < 4; ++mi)
#pragma unroll
                for (int ni = 0; ni < 4; ++ni)
                    acc[mi][ni] = __builtin_amdgcn_mfma_f32_16x16x32_bf16(av[mi], bv[ni], acc[mi][ni], 0, 0, 0);
        }
        __syncthreads();
    }

    float bias[4];
#pragma unroll
    for (int ni = 0; ni < 4; ++ni) bias[ni] = b1[e * HID + col0 + wn + ni * 16 + (lane & 15)];

#pragma unroll
    for (int mi = 0; mi < 4; ++mi) {
#pragma unroll
        for (int j = 0; j < 4; ++j) {
            int r = wm + mi * 16 + ((lane >> 4) * 4) + j;
            int gi = row0 + r;
            int p = oe + gi;
            if (gi < ce && p >= p0 && p < p1) {
                u16* hrow = H1 + (size_t)(p - p0) * HID;
#pragma unroll
                for (int ni = 0; ni < 4; ++ni) {
                    int n = col0 + wn + ni * 16 + (lane & 15);
                    hrow[n] = f2b(gelu_fast(acc[mi][ni][j] + bias[ni]));
                }
            }
        }
    }
}

// GEMM2: out[tok[p], d] += wgt[p] * ( sum_h H1[p, h] * W2b[e, d, h] + b2[e, d] )
__global__ __launch_bounds__(256) void gemm2_kernel(
    const u16* __restrict__ H1, const u16* __restrict__ W2b, const float* __restrict__ b2,
    const int* __restrict__ tok, const float* __restrict__ wgt,
    const int* __restrict__ cnt, const int* __restrict__ offs,
    const u32* __restrict__ table, float* __restrict__ out, int p0, int p1)
{
    const int NCOL = DMODEL / BN;              // 8
    const int nb = NCOL * MAXT, q = nb / 8;
    int bid = blockIdx.x;
    int swz = (bid & 7) * q + (bid >> 3);
    int tile = swz / NCOL, colb = swz % NCOL;
    u32 entry = table[tile];
    if (entry == 0xFFFFFFFFu) return;
    const int e = (int)(entry >> 20);
    const int row0 = (int)(entry & 0xFFFFFu);
    const int ce = cnt[e], oe = offs[e];
    if (oe + min(ce, row0 + BM) <= p0 || oe + row0 >= p1) return;
    const int col0 = colb * BN;

    __shared__ __align__(16) u16 As[BM * BK];
    __shared__ __align__(16) u16 Bs[BN * BK];

    const int tid = threadIdx.x;
    const int lane = tid & 63, wid = tid >> 6;
    const int wm = (wid >> 1) * 64, wn = (wid & 1) * 64;

    f32x4 acc[4][4] = {};

    const int smax = p1 - p0 - 1;
    size_t aoff[4], boff[4];
#pragma unroll
    for (int c = 0; c < 4; ++c) {
        int idx = c * 256 + tid;
        int r = idx >> 3;
        int s = (tid & 7) ^ (r & 7);
        int ai = oe + row0 + r - p0;
        ai = ai < 0 ? 0 : (ai > smax ? smax : ai);
        aoff[c] = (size_t)ai * HID + (size_t)(s * 8);
        boff[c] = ((size_t)e * DMODEL + col0 + r) * HID + (size_t)(s * 8);
    }

    for (int kt = 0; kt < HID; kt += BK) {
#pragma unroll
        for (int c = 0; c < 4; ++c) {
            int idx = c * 256 + tid;
            gload16(H1 + aoff[c] + kt, (char*)As + idx * 16);
            gload16(W2b + boff[c] + kt, (char*)Bs + idx * 16);
        }
        __syncthreads();
#pragma unroll
        for (int half = 0; half < 2; ++half) {
            s16x8 av[4], bv[4];
            int kslot = half * 4 + (lane >> 4);
#pragma unroll
            for (int mi = 0; mi < 4; ++mi) {
                int r = wm + mi * 16 + (lane & 15);
                av[mi] = *(const s16x8*)(As + r * BK + ((kslot ^ (r & 7)) * 8));
            }
#pragma unroll
            for (int ni = 0; ni < 4; ++ni) {
                int r = wn + ni * 16 + (lane & 15);
                bv[ni] = *(const s16x8*)(Bs + r * BK + ((kslot ^ (r & 7)) * 8));
            }
#pragma unroll
            for (int mi = 0; mi < 4; ++mi)
#pragma unroll
                for (int ni = 0; ni < 4; ++ni)
                    acc[mi][ni] = __builtin_amdgcn_mfma_f32_16x16x32_bf16(av[mi], bv[ni], acc[mi][ni], 0, 0, 0);
        }
        __syncthreads();
    }

    float bias[4];
#pragma unroll
    for (int ni = 0; ni < 4; ++ni) bias[ni] = b2[e * DMODEL + col0 + wn + ni * 16 + (lane & 15)];

#pragma unroll
    for (int mi = 0; mi < 4; ++mi) {
#pragma unroll
        for (int j = 0; j < 4; ++j) {
            int r = wm + mi * 16 + ((lane >> 4) * 4) + j;
            int gi = row0 + r;
            int p = oe + gi;
            if (gi < ce && p >= p0 && p < p1) {
                float w = wgt[p];
                float* orow = out + (size_t)tok[p] * DMODEL;
#pragma unroll
                for (int ni = 0; ni < 4; ++ni) {
                    int n = col0 + wn + ni * 16 + (lane & 15);
                    atomicAdd(orow + n, w * (acc[mi][ni][j] + bias[ni]));
                }
            }
        }
    }
}

// ---------------- host launcher ----------------
extern "C" void kernel_launch(void* const* d_in, const int* in_sizes, int n_in,
                              void* d_out, int out_size, void* d_ws, size_t ws_size,
                              hipStream_t stream)
{
    const float* x  = (const float*)d_in[0];
    const float* Wr = (const float*)d_in[1];
    const float* br = (const float*)d_in[2];
    const float* W1 = (const float*)d_in[3];
    const float* b1 = (const float*)d_in[4];
    const float* W2 = (const float*)d_in[5];
    const float* b2 = (const float*)d_in[6];
    float* out = (float*)d_out;

    char* ws = (char*)d_ws;
    u16* xb = (u16*)ws;                               // 16 MiB
    size_t o2 = (size_t)T_TOK * DMODEL * 2;
    int*   cnt   = (int*)(ws + o2);
    int*   fill  = (int*)(ws + o2 + 64);
    int*   offs  = (int*)(ws + o2 + 128);
    u32*   table = (u32*)(ws + o2 + 256);             // 136 entries
    int*   topi  = (int*)(ws + o2 + 2048);
    float* topw  = (float*)(ws + o2 + 2048 + (size_t)NPAIR * 4);
    int*   tok   = (int*)(ws + o2 + 2048 + (size_t)NPAIR * 8);
    float* wgt   = (float*)(ws + o2 + 2048 + (size_t)NPAIR * 12);

    const size_t WBYTES = (size_t)NEXP * DMODEL * HID * 2;   // 64 MiB each
    size_t oW2 = o2 + (2u << 20);
    size_t oW1 = oW2 + WBYTES;
    size_t oH  = oW1 + WBYTES;
    u16* W2b = (u16*)(ws + oW2);
    u16* W1b = (u16*)(ws + oW1);
    u16* H1  = (u16*)(ws + oH);

    long long cap = ((long long)ws_size - (long long)oH) / ((long long)HID * 2);
    int slice = cap >= NPAIR ? NPAIR : (cap < 1024 ? 1024 : (int)cap);

    hipMemsetAsync(out, 0, (size_t)out_size * 4, stream);
    hipMemsetAsync(cnt, 0, 256, stream);

    cvt_kernel<<<dim3(1024), 256, 0, stream>>>(x, xb, (long)T_TOK * DMODEL / 8);
    cvt_kernel<<<dim3(2048), 256, 0, stream>>>(W2, W2b, (long)NEXP * DMODEL * HID / 8);
    cvt_kernel<<<dim3(2048), 256, 0, stream>>>(W1, W1b, (long)NEXP * DMODEL * HID / 8);

    router_kernel<<<dim3(T_TOK / 4), 256, 0, stream>>>(x, Wr, br, topi, topw, cnt);
    offsets_kernel<<<dim3(1), 64, 0, stream>>>(cnt, offs, table);
    scatter_kernel<<<dim3(T_TOK / 256), 256, 0, stream>>>(topi, topw, offs, fill, tok, wgt);

    for (int pp = 0; pp < NPAIR; pp += slice) {
        int p1v = pp + slice < NPAIR ? pp + slice : NPAIR;
        gemm1_kernel<<<dim3((HID / BN) * MAXT), 256, 0, stream>>>(
            xb, W1b, b1, tok, cnt, offs, table, H1, pp, p1v);
        gemm2_kernel<<<dim3((DMODEL / BN) * MAXT), 256, 0, stream>>>(
            H1, W2b, b2, tok, wgt, cnt, offs, table, out, pp, p1v);
    }
}

// Round 4
// 817.448 us; speedup vs baseline: 1.3468x; 1.0926x over previous
//
#include <hip/hip_runtime.h>

// ---- problem dims (fixed) ----
#define T_TOK 8192      // B*S
#define DMODEL 1024
#define NEXP 8
#define TOPK 2
#define HID 4096
#define NPAIR (T_TOK*TOPK)   // 16384
#define BM 128
#define BN 128
#define BK 64
#define MAXT (NPAIR/BM + NEXP)   // 136 row-tiles upper bound

typedef unsigned short u16;
typedef unsigned int u32;
typedef short s16x8 __attribute__((ext_vector_type(8)));
typedef float f32x4 __attribute__((ext_vector_type(4)));

// fp32 -> bf16 round-to-nearest-even
__device__ __forceinline__ u16 f2b(float f) {
    union { float f; unsigned int u; } v; v.f = f;
    return (u16)((v.u + 0x7fffu + ((v.u >> 16) & 1u)) >> 16);
}

__device__ __forceinline__ s16x8 cvt8(float4 f0, float4 f1) {
    s16x8 o;
    o[0]=(short)f2b(f0.x); o[1]=(short)f2b(f0.y); o[2]=(short)f2b(f0.z); o[3]=(short)f2b(f0.w);
    o[4]=(short)f2b(f1.x); o[5]=(short)f2b(f1.y); o[6]=(short)f2b(f1.z); o[7]=(short)f2b(f1.w);
    return o;
}

// async global->LDS, 16B per lane; LDS dest linear in lane order
__device__ __forceinline__ void gload16(const void* g, void* l) {
    __builtin_amdgcn_global_load_lds(
        (const __attribute__((address_space(1))) unsigned int*)g,
        (__attribute__((address_space(3))) unsigned int*)l, 16, 0, 0);
}

// tanh-form gelu, exp/rcp in HW
__device__ __forceinline__ float gelu_fast(float v) {
    float y = 0.7978845608028654f * v * fmaf(0.044715f * v, v, 1.0f);
    float t = -2.8853900817779268f * y;   // -2y * log2(e)
    float z, r;
    asm("v_exp_f32 %0, %1" : "=v"(z) : "v"(t));
    float den = 1.0f + z;
    asm("v_rcp_f32 %0, %1" : "=v"(r) : "v"(den));
    return v * r;
}

// m204 bijective XCD swizzle over nact active blocks (grid may be larger)
__device__ __forceinline__ int xcd_swz(int bid, int nact) {
    int q = nact >> 3, r = nact & 7;
    int xcd = bid & 7, i = bid >> 3;
    return (xcd < r ? xcd * (q + 1) : r * (q + 1) + (xcd - r) * q) + i;
}

// ---------------- fp32 -> bf16 conversion ----------------
__global__ __launch_bounds__(256) void cvt_kernel(const float* __restrict__ in,
                                                  u16* __restrict__ out, long n8) {
    long stride = (long)gridDim.x * 256;
    for (long i = (long)blockIdx.x * 256 + threadIdx.x; i < n8; i += stride) {
        const float4* p = (const float4*)(in + i * 8);
        float4 f0 = p[0], f1 = p[1];
        *(s16x8*)(out + i * 8) = cvt8(f0, f1);
    }
}

// ---------------- router (fp32; selection must match reference) ----------------
__global__ __launch_bounds__(256) void router_kernel(
    const float* __restrict__ x, const float* __restrict__ Wr, const float* __restrict__ br,
    int* __restrict__ topi, float* __restrict__ topw, int* __restrict__ cnt)
{
    __shared__ float WrS[NEXP * DMODEL];
    int tid = threadIdx.x;
    const float4* Wr4 = (const float4*)Wr;
    float4* WrS4 = (float4*)WrS;
    for (int i = tid; i < NEXP * DMODEL / 4; i += 256) WrS4[i] = Wr4[i];
    __syncthreads();

    int wid = tid >> 6, lane = tid & 63;
    int t = blockIdx.x * 4 + wid;
    const float* xr = x + (size_t)t * DMODEL;

    float acc[NEXP];
#pragma unroll
    for (int e = 0; e < NEXP; ++e) acc[e] = 0.f;
    for (int i = lane; i < DMODEL; i += 64) {
        float xv = xr[i];
#pragma unroll
        for (int e = 0; e < NEXP; ++e) acc[e] = fmaf(xv, WrS[e * DMODEL + i], acc[e]);
    }
#pragma unroll
    for (int e = 0; e < NEXP; ++e) {
        float v = acc[e];
#pragma unroll
        for (int off = 32; off > 0; off >>= 1) v += __shfl_xor(v, off);
        acc[e] = v;
    }
    if (lane == 0) {
        float lg[NEXP];
#pragma unroll
        for (int e = 0; e < NEXP; ++e) lg[e] = acc[e] + br[e];
        int i1 = 0;
#pragma unroll
        for (int e = 1; e < NEXP; ++e) if (lg[e] > lg[i1]) i1 = e;
        int i2 = (i1 == 0) ? 1 : 0;
#pragma unroll
        for (int e = 0; e < NEXP; ++e) if (e != i1 && lg[e] > lg[i2]) i2 = e;
        float e2 = expf(lg[i2] - lg[i1]);
        float s = 1.f + e2;
        topi[t * 2] = i1;  topi[t * 2 + 1] = i2;
        topw[t * 2] = 1.f / s;  topw[t * 2 + 1] = e2 / s;
        atomicAdd(&cnt[i1], 1);
        atomicAdd(&cnt[i2], 1);
    }
}

// offsets + compact tile table + tile count
__global__ void offsets_kernel(const int* __restrict__ cnt, int* __restrict__ offs,
                               u32* __restrict__ table, int* __restrict__ meta) {
    if (threadIdx.x == 0 && blockIdx.x == 0) {
        int a = 0;
        for (int e = 0; e < NEXP; ++e) { offs[e] = a; a += cnt[e]; }
        offs[NEXP] = a;
        int nt = 0;
        for (int e = 0; e < NEXP; ++e)
            for (int r0 = 0; r0 < cnt[e]; r0 += BM)
                table[nt++] = ((u32)e << 20) | (u32)r0;
        meta[0] = nt;
    }
}

// wave-aggregated scatter
__global__ __launch_bounds__(256) void scatter_kernel(
    const int* __restrict__ topi, const float* __restrict__ topw,
    const int* __restrict__ offs, int* __restrict__ fill,
    int* __restrict__ tok, float* __restrict__ wgt)
{
    int t = blockIdx.x * 256 + threadIdx.x;
    int lane = threadIdx.x & 63;
#pragma unroll
    for (int s = 0; s < TOPK; ++s) {
        int e = topi[t * 2 + s];
        float w = topw[t * 2 + s];
#pragma unroll
        for (int ex = 0; ex < NEXP; ++ex) {
            unsigned long long m = __ballot(e == ex);
            if (e == ex) {
                int ldr = (int)__ffsll((unsigned long long)m) - 1;
                int base = 0;
                if (lane == ldr) base = atomicAdd(&fill[ex], (int)__popcll(m));
                base = __shfl(base, ldr);
                int mypos = base + (int)__popcll(m & ((1ull << lane) - 1ull));
                int p = offs[ex] + mypos;
                tok[p] = t;
                wgt[p] = w;
            }
        }
    }
}

// double-buffered prefetch K-loop pieces (shared by both GEMMs)
#define STAGE(Ad, Bd, kt) do {                                             \
    _Pragma("unroll") for (int c = 0; c < 4; ++c) {                        \
        int idx = c * 256 + tid;                                           \
        gload16(Agp + aoff[c] + (kt), (char*)(Ad) + idx * 16);             \
        gload16(Bgp + boff[c] + (kt), (char*)(Bd) + idx * 16);             \
    }                                                                      \
} while (0)

#define COMPUTE(Ab, Bb) do {                                               \
    _Pragma("unroll") for (int half = 0; half < 2; ++half) {               \
        s16x8 av[4], bv[4];                                                \
        int kslot = half * 4 + (lane >> 4);                                \
        _Pragma("unroll") for (int mi = 0; mi < 4; ++mi) {                 \
            int rr = wm + mi * 16 + (lane & 15);                           \
            av[mi] = *(const s16x8*)((Ab) + rr * BK + ((kslot ^ (rr & 7)) * 8)); } \
        _Pragma("unroll") for (int ni = 0; ni < 4; ++ni) {                 \
            int rr = wn + ni * 16 + (lane & 15);                           \
            bv[ni] = *(const s16x8*)((Bb) + rr * BK + ((kslot ^ (rr & 7)) * 8)); } \
        _Pragma("unroll") for (int mi = 0; mi < 4; ++mi)                   \
        _Pragma("unroll") for (int ni = 0; ni < 4; ++ni)                   \
            acc[mi][ni] = __builtin_amdgcn_mfma_f32_16x16x32_bf16(av[mi], bv[ni], acc[mi][ni], 0, 0, 0); \
    }                                                                      \
} while (0)

#define WAIT_SYNC() do {                                                   \
    asm volatile("s_waitcnt vmcnt(0)" ::: "memory");                       \
    __syncthreads();                                                       \
} while (0)

// GEMM1: H1[p, n] = gelu( sum_d xb[tok[p], d] * W1b[e, n, d] + b1[e, n] )
__global__ __launch_bounds__(256) void gemm1_kernel(
    const u16* __restrict__ xb, const u16* __restrict__ W1b, const float* __restrict__ b1,
    const int* __restrict__ tok, const int* __restrict__ cnt, const int* __restrict__ offs,
    const u32* __restrict__ table, const int* __restrict__ meta,
    u16* __restrict__ H1, int p0, int p1)
{
    const int NCOL = HID / BN;                 // 32
    int nact = NCOL * meta[0];
    int bid = blockIdx.x;
    if (bid >= nact) return;
    int swz = xcd_swz(bid, nact);
    int tile = swz / NCOL, colb = swz & (NCOL - 1);
    u32 entry = table[tile];
    const int e = (int)(entry >> 20);
    const int row0 = (int)(entry & 0xFFFFFu);
    const int ce = cnt[e], oe = offs[e];
    if (oe + min(ce, row0 + BM) <= p0 || oe + row0 >= p1) return;
    const int col0 = colb * BN;

    __shared__ __align__(16) u16 As0[BM * BK];
    __shared__ __align__(16) u16 As1[BM * BK];
    __shared__ __align__(16) u16 Bs0[BN * BK];
    __shared__ __align__(16) u16 Bs1[BN * BK];

    const int tid = threadIdx.x;
    const int lane = tid & 63, wid = tid >> 6;
    const int wm = (wid >> 1) * 64, wn = (wid & 1) * 64;

    f32x4 acc[4][4] = {};

    const u16* Agp = xb;
    const u16* Bgp = W1b;
    size_t aoff[4], boff[4];
#pragma unroll
    for (int c = 0; c < 4; ++c) {
        int idx = c * 256 + tid;
        int r = idx >> 3;
        int s = (tid & 7) ^ (r & 7);           // pre-swizzled source column chunk
        int gi = row0 + r;
        int tk = (gi < ce) ? tok[oe + gi] : tok[oe];
        aoff[c] = (size_t)tk * DMODEL + (size_t)(s * 8);
        boff[c] = ((size_t)e * HID + col0 + r) * DMODEL + (size_t)(s * 8);
    }

    const int NT = DMODEL / BK;                // 16 (even)
    STAGE(As0, Bs0, 0);
#pragma unroll 1
    for (int t = 0; t < NT; t += 2) {
        WAIT_SYNC();
        STAGE(As1, Bs1, (t + 1) * BK);
        COMPUTE(As0, Bs0);
        WAIT_SYNC();
        if (t + 2 < NT) STAGE(As0, Bs0, (t + 2) * BK);
        COMPUTE(As1, Bs1);
    }

    float bias[4];
#pragma unroll
    for (int ni = 0; ni < 4; ++ni) bias[ni] = b1[e * HID + col0 + wn + ni * 16 + (lane & 15)];

#pragma unroll
    for (int mi = 0; mi < 4; ++mi) {
#pragma unroll
        for (int j = 0; j < 4; ++j) {
            int r = wm + mi * 16 + ((lane >> 4) * 4) + j;
            int gi = row0 + r;
            int p = oe + gi;
            if (gi < ce && p >= p0 && p < p1) {
                u16* hrow = H1 + (size_t)(p - p0) * HID;
#pragma unroll
                for (int ni = 0; ni < 4; ++ni) {
                    int n = col0 + wn + ni * 16 + (lane & 15);
                    hrow[n] = f2b(gelu_fast(acc[mi][ni][j] + bias[ni]));
                }
            }
        }
    }
}

// GEMM2: out[tok[p], d] += wgt[p] * ( sum_h H1[p, h] * W2b[e, d, h] + b2[e, d] )
__global__ __launch_bounds__(256) void gemm2_kernel(
    const u16* __restrict__ H1, const u16* __restrict__ W2b, const float* __restrict__ b2,
    const int* __restrict__ tok, const float* __restrict__ wgt,
    const int* __restrict__ cnt, const int* __restrict__ offs,
    const u32* __restrict__ table, const int* __restrict__ meta,
    float* __restrict__ out, int p0, int p1)
{
    const int NCOL = DMODEL / BN;              // 8
    int nact = NCOL * meta[0];
    int bid = blockIdx.x;
    if (bid >= nact) return;
    int swz = xcd_swz(bid, nact);
    int tile = swz / NCOL, colb = swz & (NCOL - 1);
    u32 entry = table[tile];
    const int e = (int)(entry >> 20);
    const int row0 = (int)(entry & 0xFFFFFu);
    const int ce = cnt[e], oe = offs[e];
    if (oe + min(ce, row0 + BM) <= p0 || oe + row0 >= p1) return;
    const int col0 = colb * BN;

    __shared__ __align__(16) u16 As0[BM * BK];
    __shared__ __align__(16) u16 As1[BM * BK];
    __shared__ __align__(16) u16 Bs0[BN * BK];
    __shared__ __align__(16) u16 Bs1[BN * BK];

    const int tid = threadIdx.x;
    const int lane = tid & 63, wid = tid >> 6;
    const int wm = (wid >> 1) * 64, wn = (wid & 1) * 64;

    f32x4 acc[4][4] = {};

    const u16* Agp = H1;
    const u16* Bgp = W2b;
    const int smax = p1 - p0 - 1;
    size_t aoff[4], boff[4];
#pragma unroll
    for (int c = 0; c < 4; ++c) {
        int idx = c * 256 + tid;
        int r = idx >> 3;
        int s = (tid & 7) ^ (r & 7);
        int ai = oe + row0 + r - p0;
        ai = ai < 0 ? 0 : (ai > smax ? smax : ai);
        aoff[c] = (size_t)ai * HID + (size_t)(s * 8);
        boff[c] = ((size_t)e * DMODEL + col0 + r) * HID + (size_t)(s * 8);
    }

    const int NT = HID / BK;                   // 64 (even)
    STAGE(As0, Bs0, 0);
#pragma unroll 1
    for (int t = 0; t < NT; t += 2) {
        WAIT_SYNC();
        STAGE(As1, Bs1, (t + 1) * BK);
        COMPUTE(As0, Bs0);
        WAIT_SYNC();
        if (t + 2 < NT) STAGE(As0, Bs0, (t + 2) * BK);
        COMPUTE(As1, Bs1);
    }

    float bias[4];
#pragma unroll
    for (int ni = 0; ni < 4; ++ni) bias[ni] = b2[e * DMODEL + col0 + wn + ni * 16 + (lane & 15)];

#pragma unroll
    for (int mi = 0; mi < 4; ++mi) {
#pragma unroll
        for (int j = 0; j < 4; ++j) {
            int r = wm + mi * 16 + ((lane >> 4) * 4) + j;
            int gi = row0 + r;
            int p = oe + gi;
            if (gi < ce && p >= p0 && p < p1) {
                float w = wgt[p];
                float* orow = out + (size_t)tok[p] * DMODEL;
#pragma unroll
                for (int ni = 0; ni < 4; ++ni) {
                    int n = col0 + wn + ni * 16 + (lane & 15);
                    atomicAdd(orow + n, w * (acc[mi][ni][j] + bias[ni]));
                }
            }
        }
    }
}

// ---------------- host launcher ----------------
extern "C" void kernel_launch(void* const* d_in, const int* in_sizes, int n_in,
                              void* d_out, int out_size, void* d_ws, size_t ws_size,
                              hipStream_t stream)
{
    const float* x  = (const float*)d_in[0];
    const float* Wr = (const float*)d_in[1];
    const float* br = (const float*)d_in[2];
    const float* W1 = (const float*)d_in[3];
    const float* b1 = (const float*)d_in[4];
    const float* W2 = (const float*)d_in[5];
    const float* b2 = (const float*)d_in[6];
    float* out = (float*)d_out;

    char* ws = (char*)d_ws;
    u16* xb = (u16*)ws;                               // 16 MiB
    size_t o2 = (size_t)T_TOK * DMODEL * 2;
    int*   cnt   = (int*)(ws + o2);
    int*   fill  = (int*)(ws + o2 + 64);
    int*   offs  = (int*)(ws + o2 + 128);
    int*   meta  = (int*)(ws + o2 + 192);
    u32*   table = (u32*)(ws + o2 + 256);             // <=136 entries
    int*   topi  = (int*)(ws + o2 + 2048);
    float* topw  = (float*)(ws + o2 + 2048 + (size_t)NPAIR * 4);
    int*   tok   = (int*)(ws + o2 + 2048 + (size_t)NPAIR * 8);
    float* wgt   = (float*)(ws + o2 + 2048 + (size_t)NPAIR * 12);

    const size_t WBYTES = (size_t)NEXP * DMODEL * HID * 2;   // 64 MiB each
    size_t oW2 = o2 + (2u << 20);
    size_t oW1 = oW2 + WBYTES;
    size_t oH  = oW1 + WBYTES;
    u16* W2b = (u16*)(ws + oW2);
    u16* W1b = (u16*)(ws + oW1);
    u16* H1  = (u16*)(ws + oH);

    long long cap = ((long long)ws_size - (long long)oH) / ((long long)HID * 2);
    int slice = cap >= NPAIR ? NPAIR : (cap < 1024 ? 1024 : (int)cap);

    hipMemsetAsync(out, 0, (size_t)out_size * 4, stream);
    hipMemsetAsync(cnt, 0, 256, stream);

    cvt_kernel<<<dim3(1024), 256, 0, stream>>>(x, xb, (long)T_TOK * DMODEL / 8);
    cvt_kernel<<<dim3(2048), 256, 0, stream>>>(W2, W2b, (long)NEXP * DMODEL * HID / 8);
    cvt_kernel<<<dim3(2048), 256, 0, stream>>>(W1, W1b, (long)NEXP * DMODEL * HID / 8);

    router_kernel<<<dim3(T_TOK / 4), 256, 0, stream>>>(x, Wr, br, topi, topw, cnt);
    offsets_kernel<<<dim3(1), 64, 0, stream>>>(cnt, offs, table, meta);
    scatter_kernel<<<dim3(T_TOK / 256), 256, 0, stream>>>(topi, topw, offs, fill, tok, wgt);

    for (int pp = 0; pp < NPAIR; pp += slice) {
        int p1v = pp + slice < NPAIR ? pp + slice : NPAIR;
        gemm1_kernel<<<dim3((HID / BN) * MAXT), 256, 0, stream>>>(
            xb, W1b, b1, tok, cnt, offs, table, meta, H1, pp, p1v);
        gemm2_kernel<<<dim3((DMODEL / BN) * MAXT), 256, 0, stream>>>(
            H1, W2b, b2, tok, wgt, cnt, offs, table, meta, out, pp, p1v);
    }
}